// Round 1
// baseline (598.142 us; speedup 1.0000x reference)
//
#include <hip/hip_runtime.h>

// Haar DWT (stride-1, non-decimated), depthwise 2x2, right/bottom zero pad.
// x: [B, C, H, W] fp32 -> out: [B, 4*C, H, W] fp32, subband order LL,LH,HL,HH
// per input channel.

constexpr int Bn = 8, Cn = 64, Hn = 256, Wn = 256;
constexpr int ROWS_PER_BLOCK = 4;   // 256 threads = 4 waves = 4 rows

__global__ __launch_bounds__(256)
void haar_dwt_kernel(const float* __restrict__ x, float* __restrict__ out) {
    const int tid  = threadIdx.x;
    const int lane = tid & 63;        // lane within wave -> j position
    const int rib  = tid >> 6;        // row within block (0..3)

    const int rows_groups = Hn / ROWS_PER_BLOCK;          // 64
    const int rg  = blockIdx.x % rows_groups;
    const int bc  = blockIdx.x / rows_groups;             // b*Cn + c
    const int row = rg * ROWS_PER_BLOCK + rib;
    const int j0  = lane * 4;

    const size_t plane_elems = (size_t)Hn * Wn;
    const float* plane = x + (size_t)bc * plane_elems;

    // Row i: float4 + neighbor scalar (j0+4), zero past right edge
    const float* p0 = plane + (size_t)row * Wn + j0;
    float4 r0 = *reinterpret_cast<const float4*>(p0);
    float  e0 = (j0 + 4 < Wn) ? p0[4] : 0.0f;

    // Row i+1: zero row past bottom edge
    float4 r1 = make_float4(0.f, 0.f, 0.f, 0.f);
    float  e1 = 0.0f;
    if (row + 1 < Hn) {
        const float* p1 = p0 + Wn;
        r1 = *reinterpret_cast<const float4*>(p1);
        e1 = (j0 + 4 < Wn) ? p1[4] : 0.0f;
    }

    float a0[5] = {r0.x, r0.y, r0.z, r0.w, e0};
    float a1[5] = {r1.x, r1.y, r1.z, r1.w, e1};

    float4 vll, vlh, vhl, vhh;
    float* pll = reinterpret_cast<float*>(&vll);
    float* plh = reinterpret_cast<float*>(&vlh);
    float* phl = reinterpret_cast<float*>(&vhl);
    float* phh = reinterpret_cast<float*>(&vhh);

#pragma unroll
    for (int k = 0; k < 4; ++k) {
        const float x00 = a0[k], x01 = a0[k + 1];
        const float x10 = a1[k], x11 = a1[k + 1];
        const float sum0 = x00 + x01;   // row i:  lo
        const float dif0 = x00 - x01;   // row i:  hi
        const float sum1 = x10 + x11;   // row i+1: lo
        const float dif1 = x10 - x11;   // row i+1: hi
        pll[k] = 0.5f * (sum0 + sum1);
        plh[k] = 0.5f * (sum0 - sum1);
        phl[k] = 0.5f * (dif0 + dif1);
        phh[k] = 0.5f * (dif0 - dif1);
    }

    const int b = bc / Cn;
    const int c = bc % Cn;
    float* obase = out + ((size_t)(b * 4 * Cn + 4 * c)) * plane_elems
                       + (size_t)row * Wn + j0;

    *reinterpret_cast<float4*>(obase)                   = vll;
    *reinterpret_cast<float4*>(obase + plane_elems)     = vlh;
    *reinterpret_cast<float4*>(obase + 2 * plane_elems) = vhl;
    *reinterpret_cast<float4*>(obase + 3 * plane_elems) = vhh;
}

extern "C" void kernel_launch(void* const* d_in, const int* in_sizes, int n_in,
                              void* d_out, int out_size, void* d_ws, size_t ws_size,
                              hipStream_t stream) {
    const float* x = (const float*)d_in[0];
    float* out = (float*)d_out;

    const int grid = Bn * Cn * (Hn / ROWS_PER_BLOCK);  // 8*64*64 = 32768
    haar_dwt_kernel<<<grid, 256, 0, stream>>>(x, out);
}